// Round 4
// baseline (265.770 us; speedup 1.0000x reference)
//
#include <hip/hip_runtime.h>

// LightGCN propagation, CSR-by-destination formulation.
// N=100000 nodes, D=64 dims, E=1250000 edges (sizes read from in_sizes).
//
// R4 changes vs R3:
//  - k_deg_count: 8 shadow accumulators pk8[c][N] (copy-major => disjoint
//    cachelines), copy = blockIdx.x & 7. R3's single-copy u64 atomics ran at
//    21 G/s with ~100 atomics/cacheline (~29 queued/line instantaneous) --
//    testing the per-line-serialization hypothesis.
//  - slot[e] now stores {copy:3 | local_slot_within_copy}. k_unpack computes
//    per-node per-copy exclusive prefixes base8[node][copy]; k_fill places at
//    row_start[d] + base8[d][c] + local. Still zero atomics outside deg_count.

#define SCAN_CHUNK 512
#define SUM_BITS 44
#define SUM_MASK ((1ull << SUM_BITS) - 1)
#define NCOPY 8

__global__ void k_deg_count(const int* __restrict__ ei, const float* __restrict__ ea,
                            unsigned long long* __restrict__ pk8, int* __restrict__ slot,
                            int N, int E) {
    int c = blockIdx.x & (NCOPY - 1);
    unsigned long long* pk = pk8 + (size_t)c * N;
    int stride = gridDim.x * blockDim.x;
    for (int e = blockIdx.x * blockDim.x + threadIdx.x; e < E; e += stride) {
        int d = ei[E + e];
        unsigned long long q = (unsigned long long)((double)ea[e] * 4294967296.0);
        unsigned long long inc = (1ull << SUM_BITS) | q;
        unsigned long long old = atomicAdd(&pk[d], inc);
        slot[e] = (int)(old >> SUM_BITS) | (c << 27);
    }
}

// per node: merge 8 copies -> dinv, total cnt, per-copy exclusive prefix base8
__global__ void k_unpack(const unsigned long long* __restrict__ pk8,
                         float* __restrict__ dinv, int* __restrict__ cnt,
                         int* __restrict__ base8, int N) {
    int i = blockIdx.x * blockDim.x + threadIdx.x;
    if (i >= N) return;
    unsigned long long sum = 0;
    int running = 0;
    #pragma unroll
    for (int c = 0; c < NCOPY; ++c) {
        unsigned long long p = pk8[(size_t)c * N + i];
        base8[(i << 3) + c] = running;
        running += (int)(p >> SUM_BITS);
        sum += (p & SUM_MASK);
    }
    cnt[i] = running;
    double s = (double)sum * (1.0 / 4294967296.0);
    dinv[i] = (s > 0.0) ? rsqrtf((float)s) : 0.0f;
}

__global__ void k_chunk_sums(const int* __restrict__ cnt, int* __restrict__ partial, int N) {
    __shared__ int s[SCAN_CHUNK];
    int t = threadIdx.x;
    int i = blockIdx.x * SCAN_CHUNK + t;
    s[t] = (i < N) ? cnt[i] : 0;
    __syncthreads();
    for (int off = SCAN_CHUNK / 2; off > 0; off >>= 1) {
        if (t < off) s[t] += s[t + off];
        __syncthreads();
    }
    if (t == 0) partial[blockIdx.x] = s[0];
}

// single block, exclusive-scans up to 256 partials in place (nblk=196 for N=100000)
__global__ void k_scan_partials(int* __restrict__ partial, int nblk) {
    __shared__ int s[256];
    int t = threadIdx.x;
    int v = (t < nblk) ? partial[t] : 0;
    s[t] = v;
    __syncthreads();
    for (int off = 1; off < 256; off <<= 1) {
        int x = (t >= off) ? s[t - off] : 0;
        __syncthreads();
        s[t] += x;
        __syncthreads();
    }
    if (t < nblk) partial[t] = s[t] - v;  // exclusive
}

__global__ void k_scan_write(const int* __restrict__ cnt, const int* __restrict__ partial,
                             int* __restrict__ row_start, int N) {
    __shared__ int s[SCAN_CHUNK];
    int t = threadIdx.x;
    int i = blockIdx.x * SCAN_CHUNK + t;
    int v = (i < N) ? cnt[i] : 0;
    s[t] = v;
    __syncthreads();
    for (int off = 1; off < SCAN_CHUNK; off <<= 1) {
        int x = (t >= off) ? s[t - off] : 0;
        __syncthreads();
        s[t] += x;
        __syncthreads();
    }
    if (i < N) {
        int excl = s[t] - v + partial[blockIdx.x];
        row_start[i] = excl;
        if (i == N - 1) row_start[N] = excl + v;
    }
}

// no atomics: slot[e] = {copy:3 | local}; position = row_start + base8 + local
__global__ void k_fill(const int* __restrict__ ei, const float* __restrict__ ea,
                       const float* __restrict__ dinv, const int* __restrict__ row_start,
                       const int* __restrict__ slot, const int* __restrict__ base8,
                       int2* __restrict__ meta, int E) {
    int stride = gridDim.x * blockDim.x;
    for (int e = blockIdx.x * blockDim.x + threadIdx.x; e < E; e += stride) {
        int s = ei[e];
        int d = ei[E + e];
        float w = dinv[s] * ea[e] * dinv[d];
        int sl = slot[e];
        int c = (sl >> 27) & (NCOPY - 1);
        int local = sl & ((1 << 27) - 1);
        int2 m;
        m.x = s;
        m.y = __float_as_int(w);
        meta[row_start[d] + base8[(d << 3) + c] + local] = m;
    }
}

// 16-lane group per destination node; lane l owns dims 4l..4l+3 (float4).
// 4 nodes per wave. Edge loop unrolled x4 for memory-level parallelism.
// MODE: 0 = first layer  (out = alpha*(emb_row + acc), write x)
//       1 = middle layer (out += alpha*acc, write x)
//       2 = last layer   (out += alpha*acc, no x write)
template <int MODE>
__global__ void __launch_bounds__(256) k_layer(const float4* __restrict__ xin,
                                               const int2* __restrict__ meta,
                                               const int* __restrict__ row_start,
                                               float4* __restrict__ xout,
                                               float4* __restrict__ out, int N) {
    int g = (blockIdx.x * 256 + threadIdx.x) >> 4;  // group id = node
    if (g >= N) return;
    int l = threadIdx.x & 15;  // lane-in-group
    int b = row_start[g];
    int e = row_start[g + 1];

    float4 acc = make_float4(0.f, 0.f, 0.f, 0.f);
    int i = b;
    for (; i + 4 <= e; i += 4) {
        int2 m0 = meta[i];
        int2 m1 = meta[i + 1];
        int2 m2 = meta[i + 2];
        int2 m3 = meta[i + 3];
        float4 v0 = xin[m0.x * 16 + l];
        float4 v1 = xin[m1.x * 16 + l];
        float4 v2 = xin[m2.x * 16 + l];
        float4 v3 = xin[m3.x * 16 + l];
        float w0 = __int_as_float(m0.y);
        float w1 = __int_as_float(m1.y);
        float w2 = __int_as_float(m2.y);
        float w3 = __int_as_float(m3.y);
        acc.x = fmaf(v0.x, w0, acc.x);
        acc.y = fmaf(v0.y, w0, acc.y);
        acc.z = fmaf(v0.z, w0, acc.z);
        acc.w = fmaf(v0.w, w0, acc.w);
        acc.x = fmaf(v1.x, w1, acc.x);
        acc.y = fmaf(v1.y, w1, acc.y);
        acc.z = fmaf(v1.z, w1, acc.z);
        acc.w = fmaf(v1.w, w1, acc.w);
        acc.x = fmaf(v2.x, w2, acc.x);
        acc.y = fmaf(v2.y, w2, acc.y);
        acc.z = fmaf(v2.z, w2, acc.z);
        acc.w = fmaf(v2.w, w2, acc.w);
        acc.x = fmaf(v3.x, w3, acc.x);
        acc.y = fmaf(v3.y, w3, acc.y);
        acc.z = fmaf(v3.z, w3, acc.z);
        acc.w = fmaf(v3.w, w3, acc.w);
    }
    for (; i < e; ++i) {
        int2 m = meta[i];
        float4 v = xin[m.x * 16 + l];
        float w = __int_as_float(m.y);
        acc.x = fmaf(v.x, w, acc.x);
        acc.y = fmaf(v.y, w, acc.y);
        acc.z = fmaf(v.z, w, acc.z);
        acc.w = fmaf(v.w, w, acc.w);
    }

    int o = g * 16 + l;
    if (MODE == 0) {
        // fuse out_init: out = alpha*(emb_row + acc); xin here IS emb
        float4 ev = xin[o];
        float4 r;
        r.x = 0.25f * (ev.x + acc.x);
        r.y = 0.25f * (ev.y + acc.y);
        r.z = 0.25f * (ev.z + acc.z);
        r.w = 0.25f * (ev.w + acc.w);
        out[o] = r;
        xout[o] = acc;
    } else {
        float4 po = out[o];
        po.x = fmaf(0.25f, acc.x, po.x);
        po.y = fmaf(0.25f, acc.y, po.y);
        po.z = fmaf(0.25f, acc.z, po.z);
        po.w = fmaf(0.25f, acc.w, po.w);
        out[o] = po;
        if (MODE == 1) xout[o] = acc;
    }
}

static inline size_t align_up(size_t x, size_t a) { return (x + a - 1) & ~(a - 1); }

extern "C" void kernel_launch(void* const* d_in, const int* in_sizes, int n_in,
                              void* d_out, int out_size, void* d_ws, size_t ws_size,
                              hipStream_t stream) {
    const float* emb = (const float*)d_in[0];
    const float* ea  = (const float*)d_in[1];
    const int*   ei  = (const int*)d_in[2];
    float* out = (float*)d_out;

    const int D = 64;
    const int N = in_sizes[0] / D;
    const int E = in_sizes[1];

    // workspace carve (all 256B-aligned)
    char* ws = (char*)d_ws;
    size_t off = 0;
    unsigned long long* pk8 = (unsigned long long*)(ws + off);
                                            off = align_up(off + (size_t)NCOPY * N * 8, 256);
    float* dinv = (float*)(ws + off);       off = align_up(off + (size_t)N * 4, 256);
    int* cnt = (int*)(ws + off);            off = align_up(off + (size_t)N * 4, 256);
    int* row_start = (int*)(ws + off);      off = align_up(off + (size_t)(N + 1) * 4, 256);
    int* partial = (int*)(ws + off);        off = align_up(off + 1024 * 4, 256);
    int* base8 = (int*)(ws + off);          off = align_up(off + (size_t)N * NCOPY * 4, 256);
    int* slot = (int*)(ws + off);           off = align_up(off + (size_t)E * 4, 256);
    int2* meta = (int2*)(ws + off);         off = align_up(off + (size_t)E * 8, 256);
    float* x1 = (float*)(ws + off);         off = align_up(off + (size_t)N * D * 4, 256);
    float* x2 = (float*)(ws + off);         off = align_up(off + (size_t)N * D * 4, 256);
    (void)ws_size;

    hipMemsetAsync(pk8, 0, (size_t)NCOPY * N * 8, stream);

    int eb = (E + 255) / 256;
    k_deg_count<<<eb, 256, 0, stream>>>(ei, ea, pk8, slot, N, E);
    k_unpack<<<(N + 255) / 256, 256, 0, stream>>>(pk8, dinv, cnt, base8, N);

    int nblk = (N + SCAN_CHUNK - 1) / SCAN_CHUNK;  // 196 for N=100000 (must be <=256)
    k_chunk_sums<<<nblk, SCAN_CHUNK, 0, stream>>>(cnt, partial, N);
    k_scan_partials<<<1, 256, 0, stream>>>(partial, nblk);
    k_scan_write<<<nblk, SCAN_CHUNK, 0, stream>>>(cnt, partial, row_start, N);

    k_fill<<<eb, 256, 0, stream>>>(ei, ea, dinv, row_start, slot, base8, meta, E);

    int lb = (N * 16 + 255) / 256;  // 16 lanes per node
    k_layer<0><<<lb, 256, 0, stream>>>((const float4*)emb, meta, row_start,
                                       (float4*)x1, (float4*)out, N);
    k_layer<1><<<lb, 256, 0, stream>>>((const float4*)x1, meta, row_start,
                                       (float4*)x2, (float4*)out, N);
    k_layer<2><<<lb, 256, 0, stream>>>((const float4*)x2, meta, row_start,
                                       nullptr, (float4*)out, N);
}

// Round 5
// 203.333 us; speedup vs baseline: 1.3071x; 1.3071x over previous
//
#include <hip/hip_runtime.h>
#include <hip/hip_fp16.h>

// LightGCN propagation, CSR-by-destination formulation.
// N=100000 nodes, D=64 dims, E=1250000 edges (sizes read from in_sizes).
//
// R5 changes vs R4:
//  - Reverted shadow copies (R4 NULL -> device atomics are per-op capped
//    ~22 G/s at the coherence point; address spreading can't help).
//  - z-scaling: store z = dinv*x in fp16; meta weight is raw edge_attr.
//    Layer: x_new[d] = dinv[d] * sum(ea * z[s]); z_next = dinv[d]*x_new.
//    => deg-sum moves AFTER CSR build (plain fp32 segmented sum, no weighted
//    atomic), k_fill loses its two random dinv gathers, and the count atomic
//    is a bare u32.
//  - k_layer gathers fp16 (8 B/lane, 128 B/row) -- halves the dominant
//    320 MB/layer gather traffic.

#define SCAN_CHUNK 512

__global__ void k_count(const int* __restrict__ ei, unsigned int* __restrict__ cnt,
                        int* __restrict__ slot, int E) {
    int e = blockIdx.x * blockDim.x + threadIdx.x;
    if (e < E) {
        int d = ei[E + e];
        slot[e] = (int)atomicAdd(&cnt[d], 1u);
    }
}

__global__ void k_chunk_sums(const unsigned int* __restrict__ cnt, int* __restrict__ partial, int N) {
    __shared__ int s[SCAN_CHUNK];
    int t = threadIdx.x;
    int i = blockIdx.x * SCAN_CHUNK + t;
    s[t] = (i < N) ? (int)cnt[i] : 0;
    __syncthreads();
    for (int off = SCAN_CHUNK / 2; off > 0; off >>= 1) {
        if (t < off) s[t] += s[t + off];
        __syncthreads();
    }
    if (t == 0) partial[blockIdx.x] = s[0];
}

// single block, exclusive-scans up to 256 partials in place (nblk=196 for N=100000)
__global__ void k_scan_partials(int* __restrict__ partial, int nblk) {
    __shared__ int s[256];
    int t = threadIdx.x;
    int v = (t < nblk) ? partial[t] : 0;
    s[t] = v;
    __syncthreads();
    for (int off = 1; off < 256; off <<= 1) {
        int x = (t >= off) ? s[t - off] : 0;
        __syncthreads();
        s[t] += x;
        __syncthreads();
    }
    if (t < nblk) partial[t] = s[t] - v;  // exclusive
}

__global__ void k_scan_write(const unsigned int* __restrict__ cnt, const int* __restrict__ partial,
                             int* __restrict__ row_start, int N) {
    __shared__ int s[SCAN_CHUNK];
    int t = threadIdx.x;
    int i = blockIdx.x * SCAN_CHUNK + t;
    int v = (i < N) ? (int)cnt[i] : 0;
    s[t] = v;
    __syncthreads();
    for (int off = 1; off < SCAN_CHUNK; off <<= 1) {
        int x = (t >= off) ? s[t - off] : 0;
        __syncthreads();
        s[t] += x;
        __syncthreads();
    }
    if (i < N) {
        int excl = s[t] - v + partial[blockIdx.x];
        row_start[i] = excl;
        if (i == N - 1) row_start[N] = excl + v;
    }
}

// meta[row_start[d] + slot[e]] = (src, edge_attr). No atomics, no dinv gathers.
__global__ void k_fill(const int* __restrict__ ei, const float* __restrict__ ea,
                       const int* __restrict__ row_start, const int* __restrict__ slot,
                       int2* __restrict__ meta, int E) {
    int e = blockIdx.x * blockDim.x + threadIdx.x;
    if (e < E) {
        int2 m;
        m.x = ei[e];
        m.y = __float_as_int(ea[e]);
        meta[row_start[ei[E + e]] + slot[e]] = m;
    }
}

// deg[d] = sum of ea over the (now sorted) row; dinv = rsqrt. 8 lanes/node.
__global__ void k_degsum(const int2* __restrict__ meta, const int* __restrict__ row_start,
                         float* __restrict__ dinv, int N) {
    int g = (blockIdx.x * blockDim.x + threadIdx.x) >> 3;
    if (g >= N) return;
    int l = threadIdx.x & 7;
    int b = row_start[g];
    int e = row_start[g + 1];
    float s = 0.0f;
    for (int i = b + l; i < e; i += 8) s += __int_as_float(meta[i].y);
    s += __shfl_xor(s, 1);
    s += __shfl_xor(s, 2);
    s += __shfl_xor(s, 4);
    if (l == 0) dinv[g] = (s > 0.0f) ? rsqrtf(s) : 0.0f;
}

// z0 = fp16(emb * dinv[node]); one thread per float2 (2 dims)
__global__ void k_z0(const float2* __restrict__ emb2, const float* __restrict__ dinv,
                     __half2* __restrict__ z, int n2) {
    int i = blockIdx.x * blockDim.x + threadIdx.x;
    if (i < n2) {
        float s = dinv[i >> 5];
        float2 v = emb2[i];
        z[i] = __floats2half2_rn(v.x * s, v.y * s);
    }
}

union F2H {
    float2 f;
    __half2 h[2];
};

// 16-lane group per destination node; lane l owns dims 4l..4l+3.
// Gathers fp16 z rows (8 B/lane); fp32 accumulate; unroll x4 for MLP.
// MODE: 0 = first layer  (out = alpha*(emb+x_new), write z)
//       1 = middle layer (out += alpha*x_new, write z)
//       2 = last layer   (out += alpha*x_new)
template <int MODE>
__global__ void __launch_bounds__(256) k_layer(const float2* __restrict__ zin,   // N*16 float2
                                               const float4* __restrict__ emb,   // MODE0 only
                                               const int2* __restrict__ meta,
                                               const int* __restrict__ row_start,
                                               const float* __restrict__ dinv,
                                               float2* __restrict__ zout,
                                               float4* __restrict__ out, int N) {
    int g = (blockIdx.x * 256 + threadIdx.x) >> 4;
    if (g >= N) return;
    int l = threadIdx.x & 15;
    int b = row_start[g];
    int e = row_start[g + 1];

    float4 acc = make_float4(0.f, 0.f, 0.f, 0.f);
    int i = b;
    for (; i + 4 <= e; i += 4) {
        int2 m0 = meta[i];
        int2 m1 = meta[i + 1];
        int2 m2 = meta[i + 2];
        int2 m3 = meta[i + 3];
        F2H u0, u1, u2, u3;
        u0.f = zin[(size_t)m0.x * 16 + l];
        u1.f = zin[(size_t)m1.x * 16 + l];
        u2.f = zin[(size_t)m2.x * 16 + l];
        u3.f = zin[(size_t)m3.x * 16 + l];
        float w0 = __int_as_float(m0.y);
        float w1 = __int_as_float(m1.y);
        float w2 = __int_as_float(m2.y);
        float w3 = __int_as_float(m3.y);
        float2 a0 = __half22float2(u0.h[0]), b0 = __half22float2(u0.h[1]);
        float2 a1 = __half22float2(u1.h[0]), b1 = __half22float2(u1.h[1]);
        float2 a2 = __half22float2(u2.h[0]), b2 = __half22float2(u2.h[1]);
        float2 a3 = __half22float2(u3.h[0]), b3 = __half22float2(u3.h[1]);
        acc.x = fmaf(a0.x, w0, acc.x);
        acc.y = fmaf(a0.y, w0, acc.y);
        acc.z = fmaf(b0.x, w0, acc.z);
        acc.w = fmaf(b0.y, w0, acc.w);
        acc.x = fmaf(a1.x, w1, acc.x);
        acc.y = fmaf(a1.y, w1, acc.y);
        acc.z = fmaf(b1.x, w1, acc.z);
        acc.w = fmaf(b1.y, w1, acc.w);
        acc.x = fmaf(a2.x, w2, acc.x);
        acc.y = fmaf(a2.y, w2, acc.y);
        acc.z = fmaf(b2.x, w2, acc.z);
        acc.w = fmaf(b2.y, w2, acc.w);
        acc.x = fmaf(a3.x, w3, acc.x);
        acc.y = fmaf(a3.y, w3, acc.y);
        acc.z = fmaf(b3.x, w3, acc.z);
        acc.w = fmaf(b3.y, w3, acc.w);
    }
    for (; i < e; ++i) {
        int2 m = meta[i];
        F2H u;
        u.f = zin[(size_t)m.x * 16 + l];
        float w = __int_as_float(m.y);
        float2 a = __half22float2(u.h[0]), bb = __half22float2(u.h[1]);
        acc.x = fmaf(a.x, w, acc.x);
        acc.y = fmaf(a.y, w, acc.y);
        acc.z = fmaf(bb.x, w, acc.z);
        acc.w = fmaf(bb.y, w, acc.w);
    }

    float sd = dinv[g];  // broadcast
    float4 xn;
    xn.x = sd * acc.x;
    xn.y = sd * acc.y;
    xn.z = sd * acc.z;
    xn.w = sd * acc.w;

    int o = g * 16 + l;
    if (MODE == 0) {
        float4 ev = emb[o];
        float4 r;
        r.x = 0.25f * (ev.x + xn.x);
        r.y = 0.25f * (ev.y + xn.y);
        r.z = 0.25f * (ev.z + xn.z);
        r.w = 0.25f * (ev.w + xn.w);
        out[o] = r;
    } else {
        float4 po = out[o];
        po.x = fmaf(0.25f, xn.x, po.x);
        po.y = fmaf(0.25f, xn.y, po.y);
        po.z = fmaf(0.25f, xn.z, po.z);
        po.w = fmaf(0.25f, xn.w, po.w);
        out[o] = po;
    }
    if (MODE < 2) {
        F2H u;
        u.h[0] = __floats2half2_rn(sd * xn.x, sd * xn.y);
        u.h[1] = __floats2half2_rn(sd * xn.z, sd * xn.w);
        zout[o] = u.f;
    }
}

static inline size_t align_up(size_t x, size_t a) { return (x + a - 1) & ~(a - 1); }

extern "C" void kernel_launch(void* const* d_in, const int* in_sizes, int n_in,
                              void* d_out, int out_size, void* d_ws, size_t ws_size,
                              hipStream_t stream) {
    const float* emb = (const float*)d_in[0];
    const float* ea  = (const float*)d_in[1];
    const int*   ei  = (const int*)d_in[2];
    float* out = (float*)d_out;

    const int D = 64;
    const int N = in_sizes[0] / D;
    const int E = in_sizes[1];

    // workspace carve (all 256B-aligned)
    char* ws = (char*)d_ws;
    size_t off = 0;
    unsigned int* cnt = (unsigned int*)(ws + off); off = align_up(off + (size_t)N * 4, 256);
    float* dinv = (float*)(ws + off);       off = align_up(off + (size_t)N * 4, 256);
    int* row_start = (int*)(ws + off);      off = align_up(off + (size_t)(N + 1) * 4, 256);
    int* partial = (int*)(ws + off);        off = align_up(off + 1024 * 4, 256);
    int* slot = (int*)(ws + off);           off = align_up(off + (size_t)E * 4, 256);
    int2* meta = (int2*)(ws + off);         off = align_up(off + (size_t)E * 8, 256);
    __half2* zA = (__half2*)(ws + off);     off = align_up(off + (size_t)N * D * 2, 256);
    __half2* zB = (__half2*)(ws + off);     off = align_up(off + (size_t)N * D * 2, 256);
    (void)ws_size;

    hipMemsetAsync(cnt, 0, (size_t)N * 4, stream);

    int eb = (E + 255) / 256;
    k_count<<<eb, 256, 0, stream>>>(ei, cnt, slot, E);

    int nblk = (N + SCAN_CHUNK - 1) / SCAN_CHUNK;  // 196 for N=100000 (must be <=256)
    k_chunk_sums<<<nblk, SCAN_CHUNK, 0, stream>>>(cnt, partial, N);
    k_scan_partials<<<1, 256, 0, stream>>>(partial, nblk);
    k_scan_write<<<nblk, SCAN_CHUNK, 0, stream>>>(cnt, partial, row_start, N);

    k_fill<<<eb, 256, 0, stream>>>(ei, ea, row_start, slot, meta, E);
    k_degsum<<<(N * 8 + 255) / 256, 256, 0, stream>>>(meta, row_start, dinv, N);
    k_z0<<<(N * 32 + 255) / 256, 256, 0, stream>>>((const float2*)emb, dinv, zA, N * 32);

    int lb = (N * 16 + 255) / 256;  // 16 lanes per node
    // layer1: zA -> zB ; layer2: zB -> zA (z0 dead) ; layer3: zA -> (none)
    k_layer<0><<<lb, 256, 0, stream>>>((const float2*)zA, (const float4*)emb, meta,
                                       row_start, dinv, (float2*)zB, (float4*)out, N);
    k_layer<1><<<lb, 256, 0, stream>>>((const float2*)zB, nullptr, meta,
                                       row_start, dinv, (float2*)zA, (float4*)out, N);
    k_layer<2><<<lb, 256, 0, stream>>>((const float2*)zA, nullptr, meta,
                                       row_start, dinv, nullptr, (float4*)out, N);
}

// Round 6
// 163.940 us; speedup vs baseline: 1.6211x; 1.2403x over previous
//
#include <hip/hip_runtime.h>
#include <hip/hip_fp16.h>

// LightGCN propagation, CSR-by-destination formulation.
// N=100000 nodes, D=64 dims, E=1250000 edges (sizes read from in_sizes).
//
// R6 changes vs R5:
//  - ATOMIC-FREE CSR build (R3/R4/R5 established: returning device atomics
//    are per-op capped ~23 G/s chip-wide; 1.25M of them = 53us, irreducible
//    by width/address spreading). Replaced with a 2-level bucket sort:
//      P1 k_bhist   : per-chunk LDS histogram of dst>>6 -> bcnt[b*G+g]
//      P2 scans     : exclusive scan of the 400K (bucket,chunk) counts
//      P3 k_bscatter: scatter edges bucket-sorted via LDS cursors (LDS
//                     returning atomics are on-CU, no fabric cap)
//      P4 k_bfinal  : block per bucket; 64-node LDS hist+scan -> row_start,
//                     per-node sum(ea) -> dinv (absorbs k_degsum); scatter
//                     node-sorted meta.
//  - Layers (k_prop) write z only; new k_final computes
//    out = alpha*(emb + rdeg*(z1+z2+z3)), rdeg = 1/dinv. Removes 128 MB of
//    out r/w from the gather kernels.

#define G 256        // edge-chunk blocks for hist/scatter
#define SH 6         // bucket = dst >> SH
#define BNODES 64    // nodes per bucket

// ---------- P1: per-chunk bucket histogram (LDS, no device atomics) ----------
__global__ void __launch_bounds__(256) k_bhist(const int* __restrict__ ei,
                                               int* __restrict__ bcnt, int NB, int E) {
    extern __shared__ unsigned int hist[];  // NB counters
    int g = blockIdx.x, t = threadIdx.x;
    for (int b = t; b < NB; b += 256) hist[b] = 0;
    __syncthreads();
    int chunk = (E + G - 1) / G;
    int lo = g * chunk;
    int hi = min(lo + chunk, E);
    for (int i = lo + t; i < hi; i += 256) {
        int d = ei[E + i];
        atomicAdd(&hist[d >> SH], 1u);
    }
    __syncthreads();
    for (int b = t; b < NB; b += 256) bcnt[b * G + g] = (int)hist[b];
}

// ---------- P2a: 512-chunk exclusive scan + chunk sums ----------
__global__ void __launch_bounds__(512) k_scan_local(const int* __restrict__ in,
                                                    int* __restrict__ outExcl,
                                                    int* __restrict__ sums, int n) {
    __shared__ int s[512];
    int t = threadIdx.x;
    int i = blockIdx.x * 512 + t;
    int v = (i < n) ? in[i] : 0;
    s[t] = v;
    __syncthreads();
    for (int off = 1; off < 512; off <<= 1) {
        int x = (t >= off) ? s[t - off] : 0;
        __syncthreads();
        s[t] += x;
        __syncthreads();
    }
    if (i < n) outExcl[i] = s[t] - v;
    if (t == 511) sums[blockIdx.x] = s[511];
}

// ---------- P2b: single-block exclusive scan of up to 1024 chunk sums ----------
__global__ void __launch_bounds__(1024) k_scan_partials1024(int* __restrict__ p, int n) {
    __shared__ int s[1024];
    int t = threadIdx.x;
    int v = (t < n) ? p[t] : 0;
    s[t] = v;
    __syncthreads();
    for (int off = 1; off < 1024; off <<= 1) {
        int x = (t >= off) ? s[t - off] : 0;
        __syncthreads();
        s[t] += x;
        __syncthreads();
    }
    if (t < n) p[t] = s[t] - v;
}

// final(f) = sc0[f] + sums[f>>9]   (512-element scan chunks)

// ---------- P3: bucket-sorted scatter via LDS cursors ----------
__global__ void __launch_bounds__(256) k_bscatter(const int* __restrict__ ei,
                                                  const float* __restrict__ ea,
                                                  const int* __restrict__ sc0,
                                                  const int* __restrict__ sums,
                                                  int2* __restrict__ ebuf, int NB, int E) {
    extern __shared__ unsigned int cur[];  // NB cursors
    int g = blockIdx.x, t = threadIdx.x;
    for (int b = t; b < NB; b += 256) {
        int f = b * G + g;
        cur[b] = (unsigned)(sc0[f] + sums[f >> 9]);
    }
    __syncthreads();
    int chunk = (E + G - 1) / G;
    int lo = g * chunk;
    int hi = min(lo + chunk, E);
    for (int i = lo + t; i < hi; i += 256) {
        int srcv = ei[i];
        int d = ei[E + i];
        float w = ea[i];
        unsigned pos = atomicAdd(&cur[d >> SH], 1u);
        int2 m;
        m.x = srcv | ((d & (BNODES - 1)) << 25);  // src < 2^17, dlow in bits 25..30
        m.y = __float_as_int(w);
        ebuf[pos] = m;
    }
}

// ---------- P4: per-bucket node sort -> meta, row_start, dinv ----------
__global__ void __launch_bounds__(256) k_bfinal(const int2* __restrict__ ebuf,
                                                const int* __restrict__ sc0,
                                                const int* __restrict__ sums,
                                                int2* __restrict__ meta,
                                                int* __restrict__ row_start,
                                                float* __restrict__ dinv,
                                                int NB, int N, int E) {
    __shared__ unsigned int hcnt[BNODES];
    __shared__ float hsum[BNODES];
    __shared__ unsigned int hoff[BNODES];
    __shared__ unsigned int cur[BNODES];
    int b = blockIdx.x, t = threadIdx.x;
    if (t < BNODES) {
        hcnt[t] = 0;
        hsum[t] = 0.0f;
    }
    __syncthreads();
    int f0 = b * G;
    int e0 = sc0[f0] + sums[f0 >> 9];
    int e1 = (b + 1 < NB) ? (sc0[f0 + G] + sums[(f0 + G) >> 9]) : E;
    for (int i = e0 + t; i < e1; i += 256) {
        int2 m = ebuf[i];
        int dl = (m.x >> 25) & (BNODES - 1);
        atomicAdd(&hcnt[dl], 1u);
        atomicAdd(&hsum[dl], __int_as_float(m.y));
    }
    __syncthreads();
    if (t == 0) {
        unsigned r = 0;
        for (int k = 0; k < BNODES; ++k) {
            hoff[k] = r;
            r += hcnt[k];
        }
    }
    __syncthreads();
    if (t < BNODES) {
        cur[t] = hoff[t];
        int node = (b << SH) + t;
        if (node < N) {
            row_start[node] = e0 + (int)hoff[t];
            float s = hsum[t];
            dinv[node] = (s > 0.0f) ? rsqrtf(s) : 0.0f;
        }
    }
    if (b == 0 && t == 0) row_start[N] = E;
    __syncthreads();
    for (int i = e0 + t; i < e1; i += 256) {
        int2 m = ebuf[i];
        int dl = (m.x >> 25) & (BNODES - 1);
        unsigned p = atomicAdd(&cur[dl], 1u);
        int2 o;
        o.x = m.x & ((1 << 25) - 1);
        o.y = m.y;
        meta[e0 + (int)p] = o;
    }
}

// ---------- z0 = fp16(emb * dinv[node]) ----------
__global__ void k_z0(const float2* __restrict__ emb2, const float* __restrict__ dinv,
                     __half2* __restrict__ z, int n2) {
    int i = blockIdx.x * blockDim.x + threadIdx.x;
    if (i < n2) {
        float s = dinv[i >> 5];
        float2 v = emb2[i];
        z[i] = __floats2half2_rn(v.x * s, v.y * s);
    }
}

union F2H {
    float2 f;
    __half2 h[2];
};

// ---------- propagation: z_next = dinv^2 * sum(ea * z[src]) ----------
// 16-lane group per destination node; lane l owns dims 4l..4l+3 (fp16 pair-of-half2).
__global__ void __launch_bounds__(256) k_prop(const float2* __restrict__ zin,
                                              const int2* __restrict__ meta,
                                              const int* __restrict__ row_start,
                                              const float* __restrict__ dinv,
                                              float2* __restrict__ zout, int N) {
    int g = (blockIdx.x * 256 + threadIdx.x) >> 4;
    if (g >= N) return;
    int l = threadIdx.x & 15;
    int b = row_start[g];
    int e = row_start[g + 1];

    float4 acc = make_float4(0.f, 0.f, 0.f, 0.f);
    int i = b;
    for (; i + 4 <= e; i += 4) {
        int2 m0 = meta[i];
        int2 m1 = meta[i + 1];
        int2 m2 = meta[i + 2];
        int2 m3 = meta[i + 3];
        F2H u0, u1, u2, u3;
        u0.f = zin[(size_t)m0.x * 16 + l];
        u1.f = zin[(size_t)m1.x * 16 + l];
        u2.f = zin[(size_t)m2.x * 16 + l];
        u3.f = zin[(size_t)m3.x * 16 + l];
        float w0 = __int_as_float(m0.y);
        float w1 = __int_as_float(m1.y);
        float w2 = __int_as_float(m2.y);
        float w3 = __int_as_float(m3.y);
        float2 a0 = __half22float2(u0.h[0]), b0 = __half22float2(u0.h[1]);
        float2 a1 = __half22float2(u1.h[0]), b1 = __half22float2(u1.h[1]);
        float2 a2 = __half22float2(u2.h[0]), b2 = __half22float2(u2.h[1]);
        float2 a3 = __half22float2(u3.h[0]), b3 = __half22float2(u3.h[1]);
        acc.x = fmaf(a0.x, w0, acc.x);
        acc.y = fmaf(a0.y, w0, acc.y);
        acc.z = fmaf(b0.x, w0, acc.z);
        acc.w = fmaf(b0.y, w0, acc.w);
        acc.x = fmaf(a1.x, w1, acc.x);
        acc.y = fmaf(a1.y, w1, acc.y);
        acc.z = fmaf(b1.x, w1, acc.z);
        acc.w = fmaf(b1.y, w1, acc.w);
        acc.x = fmaf(a2.x, w2, acc.x);
        acc.y = fmaf(a2.y, w2, acc.y);
        acc.z = fmaf(b2.x, w2, acc.z);
        acc.w = fmaf(b2.y, w2, acc.w);
        acc.x = fmaf(a3.x, w3, acc.x);
        acc.y = fmaf(a3.y, w3, acc.y);
        acc.z = fmaf(b3.x, w3, acc.z);
        acc.w = fmaf(b3.y, w3, acc.w);
    }
    for (; i < e; ++i) {
        int2 m = meta[i];
        F2H u;
        u.f = zin[(size_t)m.x * 16 + l];
        float w = __int_as_float(m.y);
        float2 a = __half22float2(u.h[0]), bb = __half22float2(u.h[1]);
        acc.x = fmaf(a.x, w, acc.x);
        acc.y = fmaf(a.y, w, acc.y);
        acc.z = fmaf(bb.x, w, acc.z);
        acc.w = fmaf(bb.y, w, acc.w);
    }

    float sd = dinv[g];
    float s2 = sd * sd;
    F2H u;
    u.h[0] = __floats2half2_rn(s2 * acc.x, s2 * acc.y);
    u.h[1] = __floats2half2_rn(s2 * acc.z, s2 * acc.w);
    zout[g * 16 + l] = u.f;
}

// ---------- final: out = alpha * (emb + rdeg*(z1+z2+z3)) ----------
__global__ void k_final(const float4* __restrict__ emb, const float2* __restrict__ z1,
                        const float2* __restrict__ z2, const float2* __restrict__ z3,
                        const float* __restrict__ dinv, float4* __restrict__ out, int n16) {
    int i = blockIdx.x * blockDim.x + threadIdx.x;
    if (i >= n16) return;
    float dv = dinv[i >> 4];
    float rd = (dv > 0.0f) ? (1.0f / dv) : 0.0f;
    F2H u1, u2, u3;
    u1.f = z1[i];
    u2.f = z2[i];
    u3.f = z3[i];
    float2 a1 = __half22float2(u1.h[0]), b1 = __half22float2(u1.h[1]);
    float2 a2 = __half22float2(u2.h[0]), b2 = __half22float2(u2.h[1]);
    float2 a3 = __half22float2(u3.h[0]), b3 = __half22float2(u3.h[1]);
    float4 ev = emb[i];
    float4 r;
    r.x = 0.25f * fmaf(rd, a1.x + a2.x + a3.x, ev.x);
    r.y = 0.25f * fmaf(rd, a1.y + a2.y + a3.y, ev.y);
    r.z = 0.25f * fmaf(rd, b1.x + b2.x + b3.x, ev.z);
    r.w = 0.25f * fmaf(rd, b1.y + b2.y + b3.y, ev.w);
    out[i] = r;
}

static inline size_t align_up(size_t x, size_t a) { return (x + a - 1) & ~(a - 1); }

extern "C" void kernel_launch(void* const* d_in, const int* in_sizes, int n_in,
                              void* d_out, int out_size, void* d_ws, size_t ws_size,
                              hipStream_t stream) {
    const float* emb = (const float*)d_in[0];
    const float* ea  = (const float*)d_in[1];
    const int*   ei  = (const int*)d_in[2];
    float* out = (float*)d_out;

    const int D = 64;
    const int N = in_sizes[0] / D;
    const int E = in_sizes[1];

    const int NB = (N + BNODES - 1) / BNODES;   // 1563
    const int NS = NB * G;                      // 400128
    const int nchunk = (NS + 511) / 512;        // 782 (must be <= 1024)

    // workspace carve (all 256B-aligned)
    char* ws = (char*)d_ws;
    size_t off = 0;
    int* bcnt = (int*)(ws + off);           off = align_up(off + (size_t)NS * 4, 256);
    int* sc0 = (int*)(ws + off);            off = align_up(off + (size_t)NS * 4, 256);
    int* sums = (int*)(ws + off);           off = align_up(off + 1024 * 4, 256);
    int* row_start = (int*)(ws + off);      off = align_up(off + (size_t)(N + 1) * 4, 256);
    float* dinv = (float*)(ws + off);       off = align_up(off + (size_t)N * 4, 256);
    int2* ebuf = (int2*)(ws + off);         off = align_up(off + (size_t)E * 8, 256);
    int2* meta = (int2*)(ws + off);         off = align_up(off + (size_t)E * 8, 256);
    __half2* z0 = (__half2*)(ws + off);     off = align_up(off + (size_t)N * D * 2, 256);
    __half2* z1 = (__half2*)(ws + off);     off = align_up(off + (size_t)N * D * 2, 256);
    __half2* z2 = (__half2*)(ws + off);     off = align_up(off + (size_t)N * D * 2, 256);
    __half2* z3 = (__half2*)(ws + off);     off = align_up(off + (size_t)N * D * 2, 256);
    (void)ws_size;

    // ---- CSR build, atomic-free ----
    k_bhist<<<G, 256, NB * 4, stream>>>(ei, bcnt, NB, E);
    k_scan_local<<<nchunk, 512, 0, stream>>>(bcnt, sc0, sums, NS);
    k_scan_partials1024<<<1, 1024, 0, stream>>>(sums, nchunk);
    k_bscatter<<<G, 256, NB * 4, stream>>>(ei, ea, sc0, sums, ebuf, NB, E);
    k_bfinal<<<NB, 256, 0, stream>>>(ebuf, sc0, sums, meta, row_start, dinv, NB, N, E);

    // ---- propagation ----
    k_z0<<<(N * 32 + 255) / 256, 256, 0, stream>>>((const float2*)emb, dinv, z0, N * 32);

    int lb = (N * 16 + 255) / 256;
    k_prop<<<lb, 256, 0, stream>>>((const float2*)z0, meta, row_start, dinv, (float2*)z1, N);
    k_prop<<<lb, 256, 0, stream>>>((const float2*)z1, meta, row_start, dinv, (float2*)z2, N);
    k_prop<<<lb, 256, 0, stream>>>((const float2*)z2, meta, row_start, dinv, (float2*)z3, N);

    k_final<<<(N * 16 + 255) / 256, 256, 0, stream>>>((const float4*)emb, (const float2*)z1,
                                                      (const float2*)z2, (const float2*)z3,
                                                      dinv, (float4*)out, N * 16);
}

// Round 7
// 148.783 us; speedup vs baseline: 1.7863x; 1.1019x over previous
//
#include <hip/hip_runtime.h>
#include <hip/hip_fp16.h>

// LightGCN propagation, CSR-by-destination formulation.
// N=100000 nodes, D=64 dims, E=1250000 edges (sizes read from in_sizes).
//
// R7 changes vs R6:
//  - meta packed to 4 B: src(17b) | q15 weight (round(ea*32767), abs err 3e-5).
//    dinv still computed from fp32 sums in k_bfinal. Halves meta stream in the
//    3 props and k_bfinal's scattered writes.
//  - k_final fused into prop-3 (MODE=1): out = alpha*(emb + rd*z1 + rd*z2 +
//    sd*acc). Removes the 90 MB final pass + 12.8 MB z3 write.
//  - prop gather loop unrolled x8 (MLP probe: props were ~5 TB/s effective,
//    below L2/L3 ceiling -> latency-bound hypothesis).

#define G 256        // edge-chunk blocks for hist/scatter
#define SH 6         // bucket = dst >> SH
#define BNODES 64    // nodes per bucket
#define WINV (1.0f / 32767.0f)

// ---------- P1: per-chunk bucket histogram (LDS, no device atomics) ----------
__global__ void __launch_bounds__(256) k_bhist(const int* __restrict__ ei,
                                               int* __restrict__ bcnt, int NB, int E) {
    extern __shared__ unsigned int hist[];  // NB counters
    int g = blockIdx.x, t = threadIdx.x;
    for (int b = t; b < NB; b += 256) hist[b] = 0;
    __syncthreads();
    int chunk = (E + G - 1) / G;
    int lo = g * chunk;
    int hi = min(lo + chunk, E);
    for (int i = lo + t; i < hi; i += 256) {
        int d = ei[E + i];
        atomicAdd(&hist[d >> SH], 1u);
    }
    __syncthreads();
    for (int b = t; b < NB; b += 256) bcnt[b * G + g] = (int)hist[b];
}

// ---------- P2a: 512-chunk exclusive scan + chunk sums ----------
__global__ void __launch_bounds__(512) k_scan_local(const int* __restrict__ in,
                                                    int* __restrict__ outExcl,
                                                    int* __restrict__ sums, int n) {
    __shared__ int s[512];
    int t = threadIdx.x;
    int i = blockIdx.x * 512 + t;
    int v = (i < n) ? in[i] : 0;
    s[t] = v;
    __syncthreads();
    for (int off = 1; off < 512; off <<= 1) {
        int x = (t >= off) ? s[t - off] : 0;
        __syncthreads();
        s[t] += x;
        __syncthreads();
    }
    if (i < n) outExcl[i] = s[t] - v;
    if (t == 511) sums[blockIdx.x] = s[511];
}

// ---------- P2b: single-block exclusive scan of up to 1024 chunk sums ----------
__global__ void __launch_bounds__(1024) k_scan_partials1024(int* __restrict__ p, int n) {
    __shared__ int s[1024];
    int t = threadIdx.x;
    int v = (t < n) ? p[t] : 0;
    s[t] = v;
    __syncthreads();
    for (int off = 1; off < 1024; off <<= 1) {
        int x = (t >= off) ? s[t - off] : 0;
        __syncthreads();
        s[t] += x;
        __syncthreads();
    }
    if (t < n) p[t] = s[t] - v;
}

// final(f) = sc0[f] + sums[f>>9]   (512-element scan chunks)

// ---------- P3: bucket-sorted scatter via LDS cursors ----------
__global__ void __launch_bounds__(256) k_bscatter(const int* __restrict__ ei,
                                                  const float* __restrict__ ea,
                                                  const int* __restrict__ sc0,
                                                  const int* __restrict__ sums,
                                                  int2* __restrict__ ebuf, int NB, int E) {
    extern __shared__ unsigned int cur[];  // NB cursors
    int g = blockIdx.x, t = threadIdx.x;
    for (int b = t; b < NB; b += 256) {
        int f = b * G + g;
        cur[b] = (unsigned)(sc0[f] + sums[f >> 9]);
    }
    __syncthreads();
    int chunk = (E + G - 1) / G;
    int lo = g * chunk;
    int hi = min(lo + chunk, E);
    for (int i = lo + t; i < hi; i += 256) {
        int srcv = ei[i];
        int d = ei[E + i];
        float w = ea[i];
        unsigned pos = atomicAdd(&cur[d >> SH], 1u);
        int2 m;
        m.x = srcv | ((d & (BNODES - 1)) << 25);  // src < 2^17, dlow in bits 25..30
        m.y = __float_as_int(w);
        ebuf[pos] = m;
    }
}

// ---------- P4: per-bucket node sort -> meta(u32), row_start, dinv ----------
__global__ void __launch_bounds__(256) k_bfinal(const int2* __restrict__ ebuf,
                                                const int* __restrict__ sc0,
                                                const int* __restrict__ sums,
                                                unsigned int* __restrict__ meta,
                                                int* __restrict__ row_start,
                                                float* __restrict__ dinv,
                                                int NB, int N, int E) {
    __shared__ unsigned int hcnt[BNODES];
    __shared__ float hsum[BNODES];
    __shared__ unsigned int hoff[BNODES];
    __shared__ unsigned int cur[BNODES];
    int b = blockIdx.x, t = threadIdx.x;
    if (t < BNODES) {
        hcnt[t] = 0;
        hsum[t] = 0.0f;
    }
    __syncthreads();
    int f0 = b * G;
    int e0 = sc0[f0] + sums[f0 >> 9];
    int e1 = (b + 1 < NB) ? (sc0[f0 + G] + sums[(f0 + G) >> 9]) : E;
    for (int i = e0 + t; i < e1; i += 256) {
        int2 m = ebuf[i];
        int dl = (m.x >> 25) & (BNODES - 1);
        atomicAdd(&hcnt[dl], 1u);
        atomicAdd(&hsum[dl], __int_as_float(m.y));
    }
    __syncthreads();
    if (t == 0) {
        unsigned r = 0;
        for (int k = 0; k < BNODES; ++k) {
            hoff[k] = r;
            r += hcnt[k];
        }
    }
    __syncthreads();
    if (t < BNODES) {
        cur[t] = hoff[t];
        int node = (b << SH) + t;
        if (node < N) {
            row_start[node] = e0 + (int)hoff[t];
            float s = hsum[t];
            dinv[node] = (s > 0.0f) ? rsqrtf(s) : 0.0f;
        }
    }
    if (b == 0 && t == 0) row_start[N] = E;
    __syncthreads();
    for (int i = e0 + t; i < e1; i += 256) {
        int2 m = ebuf[i];
        int dl = (m.x >> 25) & (BNODES - 1);
        unsigned p = atomicAdd(&cur[dl], 1u);
        float w = __int_as_float(m.y);
        unsigned q = (unsigned)__float2int_rn(w * 32767.0f);
        q = min(q, 32767u);
        meta[e0 + (int)p] = (unsigned)(m.x & ((1 << 17) - 1)) | (q << 17);
    }
}

// ---------- z0 = fp16(emb * dinv[node]) ----------
__global__ void k_z0(const float2* __restrict__ emb2, const float* __restrict__ dinv,
                     __half2* __restrict__ z, int n2) {
    int i = blockIdx.x * blockDim.x + threadIdx.x;
    if (i < n2) {
        float s = dinv[i >> 5];
        float2 v = emb2[i];
        z[i] = __floats2half2_rn(v.x * s, v.y * s);
    }
}

union F2H {
    float2 f;
    __half2 h[2];
};

// ---------- propagation: x_new = dinv * sum(w * z[src]); z_new = dinv*x_new ----
// 16-lane group per destination node; lane l owns dims 4l..4l+3.
// MODE 0: write zout = dinv^2*acc.   MODE 1 (last layer, fused final):
//   out = 0.25*(emb + rd*z1 + rd*z2 + sd*acc), rd = 1/dinv.
template <int MODE>
__global__ void __launch_bounds__(256) k_prop(const float2* __restrict__ zin,
                                              const unsigned int* __restrict__ meta,
                                              const int* __restrict__ row_start,
                                              const float* __restrict__ dinv,
                                              float2* __restrict__ zout,
                                              const float4* __restrict__ emb,
                                              const float2* __restrict__ z1,
                                              const float2* __restrict__ z2,
                                              float4* __restrict__ out, int N) {
    int g = (blockIdx.x * 256 + threadIdx.x) >> 4;
    if (g >= N) return;
    int l = threadIdx.x & 15;
    int b = row_start[g];
    int e = row_start[g + 1];

    float4 acc = make_float4(0.f, 0.f, 0.f, 0.f);
    int i = b;
    for (; i + 8 <= e; i += 8) {
        unsigned mm[8];
        F2H uu[8];
        #pragma unroll
        for (int k = 0; k < 8; ++k) mm[k] = meta[i + k];
        #pragma unroll
        for (int k = 0; k < 8; ++k) uu[k].f = zin[(size_t)(mm[k] & 0x1FFFFu) * 16 + l];
        #pragma unroll
        for (int k = 0; k < 8; ++k) {
            float w = (float)(mm[k] >> 17) * WINV;
            float2 a = __half22float2(uu[k].h[0]), bb = __half22float2(uu[k].h[1]);
            acc.x = fmaf(a.x, w, acc.x);
            acc.y = fmaf(a.y, w, acc.y);
            acc.z = fmaf(bb.x, w, acc.z);
            acc.w = fmaf(bb.y, w, acc.w);
        }
    }
    for (; i + 4 <= e; i += 4) {
        unsigned mm[4];
        F2H uu[4];
        #pragma unroll
        for (int k = 0; k < 4; ++k) mm[k] = meta[i + k];
        #pragma unroll
        for (int k = 0; k < 4; ++k) uu[k].f = zin[(size_t)(mm[k] & 0x1FFFFu) * 16 + l];
        #pragma unroll
        for (int k = 0; k < 4; ++k) {
            float w = (float)(mm[k] >> 17) * WINV;
            float2 a = __half22float2(uu[k].h[0]), bb = __half22float2(uu[k].h[1]);
            acc.x = fmaf(a.x, w, acc.x);
            acc.y = fmaf(a.y, w, acc.y);
            acc.z = fmaf(bb.x, w, acc.z);
            acc.w = fmaf(bb.y, w, acc.w);
        }
    }
    for (; i < e; ++i) {
        unsigned m = meta[i];
        F2H u;
        u.f = zin[(size_t)(m & 0x1FFFFu) * 16 + l];
        float w = (float)(m >> 17) * WINV;
        float2 a = __half22float2(u.h[0]), bb = __half22float2(u.h[1]);
        acc.x = fmaf(a.x, w, acc.x);
        acc.y = fmaf(a.y, w, acc.y);
        acc.z = fmaf(bb.x, w, acc.z);
        acc.w = fmaf(bb.y, w, acc.w);
    }

    float sd = dinv[g];
    int o = g * 16 + l;
    if (MODE == 0) {
        float s2 = sd * sd;
        F2H u;
        u.h[0] = __floats2half2_rn(s2 * acc.x, s2 * acc.y);
        u.h[1] = __floats2half2_rn(s2 * acc.z, s2 * acc.w);
        zout[o] = u.f;
    } else {
        float rd = (sd > 0.0f) ? (1.0f / sd) : 0.0f;
        F2H u1, u2;
        u1.f = z1[o];
        u2.f = z2[o];
        float2 a1 = __half22float2(u1.h[0]), b1 = __half22float2(u1.h[1]);
        float2 a2 = __half22float2(u2.h[0]), b2 = __half22float2(u2.h[1]);
        float4 ev = emb[o];
        float4 r;
        r.x = 0.25f * (ev.x + rd * (a1.x + a2.x) + sd * acc.x);
        r.y = 0.25f * (ev.y + rd * (a1.y + a2.y) + sd * acc.y);
        r.z = 0.25f * (ev.z + rd * (b1.x + b2.x) + sd * acc.z);
        r.w = 0.25f * (ev.w + rd * (b1.y + b2.y) + sd * acc.w);
        out[o] = r;
    }
}

static inline size_t align_up(size_t x, size_t a) { return (x + a - 1) & ~(a - 1); }

extern "C" void kernel_launch(void* const* d_in, const int* in_sizes, int n_in,
                              void* d_out, int out_size, void* d_ws, size_t ws_size,
                              hipStream_t stream) {
    const float* emb = (const float*)d_in[0];
    const float* ea  = (const float*)d_in[1];
    const int*   ei  = (const int*)d_in[2];
    float* out = (float*)d_out;

    const int D = 64;
    const int N = in_sizes[0] / D;
    const int E = in_sizes[1];

    const int NB = (N + BNODES - 1) / BNODES;   // 1563
    const int NS = NB * G;                      // 400128
    const int nchunk = (NS + 511) / 512;        // 782 (must be <= 1024)

    // workspace carve (all 256B-aligned)
    char* ws = (char*)d_ws;
    size_t off = 0;
    int* bcnt = (int*)(ws + off);           off = align_up(off + (size_t)NS * 4, 256);
    int* sc0 = (int*)(ws + off);            off = align_up(off + (size_t)NS * 4, 256);
    int* sums = (int*)(ws + off);           off = align_up(off + 1024 * 4, 256);
    int* row_start = (int*)(ws + off);      off = align_up(off + (size_t)(N + 1) * 4, 256);
    float* dinv = (float*)(ws + off);       off = align_up(off + (size_t)N * 4, 256);
    int2* ebuf = (int2*)(ws + off);         off = align_up(off + (size_t)E * 8, 256);
    unsigned int* meta = (unsigned int*)(ws + off); off = align_up(off + (size_t)E * 4, 256);
    __half2* z0 = (__half2*)(ws + off);     off = align_up(off + (size_t)N * D * 2, 256);
    __half2* z1 = (__half2*)(ws + off);     off = align_up(off + (size_t)N * D * 2, 256);
    __half2* z2 = (__half2*)(ws + off);     off = align_up(off + (size_t)N * D * 2, 256);
    (void)ws_size;

    // ---- CSR build, atomic-free ----
    k_bhist<<<G, 256, NB * 4, stream>>>(ei, bcnt, NB, E);
    k_scan_local<<<nchunk, 512, 0, stream>>>(bcnt, sc0, sums, NS);
    k_scan_partials1024<<<1, 1024, 0, stream>>>(sums, nchunk);
    k_bscatter<<<G, 256, NB * 4, stream>>>(ei, ea, sc0, sums, ebuf, NB, E);
    k_bfinal<<<NB, 256, 0, stream>>>(ebuf, sc0, sums, meta, row_start, dinv, NB, N, E);

    // ---- propagation ----
    k_z0<<<(N * 32 + 255) / 256, 256, 0, stream>>>((const float2*)emb, dinv, z0, N * 32);

    int lb = (N * 16 + 255) / 256;
    k_prop<0><<<lb, 256, 0, stream>>>((const float2*)z0, meta, row_start, dinv,
                                      (float2*)z1, nullptr, nullptr, nullptr, nullptr, N);
    k_prop<0><<<lb, 256, 0, stream>>>((const float2*)z1, meta, row_start, dinv,
                                      (float2*)z2, nullptr, nullptr, nullptr, nullptr, N);
    k_prop<1><<<lb, 256, 0, stream>>>((const float2*)z2, meta, row_start, dinv,
                                      nullptr, (const float4*)emb, (const float2*)z1,
                                      (const float2*)z2, (float4*)out, N);
}